// Round 5
// baseline (474.908 us; speedup 1.0000x reference)
//
#include <hip/hip_runtime.h>
#include <math.h>

#define BATCH   131072
#define OUTD    700
#define H1D     25
#define H2D     20

// ===== two-kernel decoupled path (12.5 MB workspace, same footprint as R0) ====
// K1: 4-way-split f64 frontend (R2-proven arithmetic) -> h2f (f32) + scales.
// K2: f32 backend GEMM + scale + store (R0-proven structure, 8 blocks/CU).
// Decoupling removes R2's problem: the frontend's 37 KB LDS no longer caps
// the backend's occupancy, and no barrier serializes the two phases within a
// block. Every value is produced by the exact same f64 fma/tanh/cast chain as
// the R2 passing kernel -> bit-identical output.

#define WS_H2F_OFF   ((size_t)0)                          // BATCH*20 f32 = 10.5 MB
#define WS_SCL_OFF   ((size_t)BATCH * H2D * 4)            // BATCH*4 f32  =  2 MB
#define WS_NEED      (WS_SCL_OFF + (size_t)BATCH * 16)

// ---------------- K1: 4-way-split frontend ----------------
#define F_BLK   256
#define F_SPB   64
#define F_NBLK  (BATCH / F_SPB)            // 2048
#define S1PAD   27
#define S2PAD   21

__global__ __launch_bounds__(F_BLK) void frontend_split_kernel(
    const float* __restrict__ x,
    const float* __restrict__ W1, const float* __restrict__ b1,
    const float* __restrict__ W2, const float* __restrict__ b2,
    const float* __restrict__ W3, const float* __restrict__ b3,
    float* __restrict__ h2f_out, float4* __restrict__ scl_out)
{
    __shared__ double w1d[2 * H1D];
    __shared__ double b1d[H1D];
    __shared__ double w2d[H1D * H2D];
    __shared__ double b2d[H2D];
    __shared__ float  xgs[50];
    __shared__ double cwd[50];
    __shared__ double cgd[4][H2D];
    __shared__ double cbd[4];
    __shared__ double sh1d[F_SPB * S1PAD];
    __shared__ double sh2d[F_SPB * S2PAD];
    __shared__ __align__(16) float sh2f[F_SPB * H2D];
    __shared__ __align__(16) float ssc4[F_SPB * 4];

    const int t  = threadIdx.x;
    const int ls = t & 63;       // sample within block
    const int lq = t >> 6;       // 0..3: quarter of the front-end work

    // ---- stage constants (identical to R2) ----
    if (t < 2 * H1D) w1d[t] = (double)W1[t];
    if (t < H1D)     b1d[t] = (double)b1[t];
    for (int i = t; i < H1D * H2D; i += F_BLK) w2d[i] = (double)W2[i];
    if (t < H2D)     b2d[t] = (double)b2[t];
    if (t < 50) {
        // match np.logspace(-7,0,50).astype(float32); volatile blocks fma
        volatile double m = (double)t * (7.0 / 49.0);
        double e = m + (-7.0);
        xgs[t] = (t == 49) ? 1.0f : (float)pow(10.0, e);
    }
    __syncthreads();

    if (t < 50) {
        float xp = (t < 49) ? xgs[t + 1] : xgs[t];
        float xm = (t > 0)  ? xgs[t - 1] : xgs[t];
        cwd[t] = 0.5 * ((double)xp - (double)xm);
    }
    __syncthreads();

    if (t < 4 * H2D) {
        const int q = t / H2D, k = t % H2D;
        const float* col = W3 + k * OUTD;
        double acc = 0.0;
        if (q == 0) {
            for (int i = 0; i < 50; ++i)
                acc = fma(cwd[i], (double)col[50 + i] + (double)col[100 + i], acc);
        } else {
            const int off = 100 + 50 * q;
            for (int i = 0; i < 50; ++i)
                acc = fma(cwd[i], (double)col[off + i], acc);
        }
        cgd[q][k] = acc;
    }
    if (t < 4) {
        const int q = t;
        double acc = 0.0;
        if (q == 0) {
            for (int i = 0; i < 50; ++i)
                acc = fma(cwd[i], (double)b3[50 + i] + (double)b3[100 + i], acc);
        } else {
            const int off = 100 + 50 * q;
            for (int i = 0; i < 50; ++i)
                acc = fma(cwd[i], (double)b3[off + i], acc);
        }
        cbd[q] = acc;
    }
    __syncthreads();

    // ---- F1: h1[k] for k%4==lq ----
    {
        const int sid = blockIdx.x * F_SPB + ls;
        const double x0 = (double)x[sid * 2 + 0];
        const double x1 = (double)x[sid * 2 + 1];
        for (int k = lq; k < H1D; k += 4)
            sh1d[ls * S1PAD + k] =
                tanh(fma(x0, w1d[k], fma(x1, w1d[H1D + k], b1d[k])));
    }
    __syncthreads();

    // ---- F2: h2[m] for m%4==lq; k-chain in original order ----
    {
        double acc2[5];
        #pragma unroll
        for (int i = 0; i < 5; ++i) acc2[i] = b2d[4 * i + lq];
        for (int k = 0; k < H1D; ++k) {
            const double hk = sh1d[ls * S1PAD + k];
            #pragma unroll
            for (int i = 0; i < 5; ++i)
                acc2[i] = fma(hk, w2d[k * H2D + 4 * i + lq], acc2[i]);
        }
        #pragma unroll
        for (int i = 0; i < 5; ++i) {
            const double h2v = tanh(acc2[i]);
            sh2d[ls * S2PAD + 4 * i + lq] = h2v;
            sh2f[ls * H2D  + 4 * i + lq] = (float)h2v;
        }
    }
    __syncthreads();

    // ---- F3: scale lq for sample ls ----
    {
        double acc = cbd[lq];
        #pragma unroll
        for (int k = 0; k < H2D; ++k)
            acc = fma(sh2d[ls * S2PAD + k], cgd[lq][k], acc);
        const double num = (lq & 1) ? 3.0 : 1.0;   // 1/g, 3/v, 1/v3, 3/v8
        ssc4[ls * 4 + lq] = (float)(num / acc);
    }
    __syncthreads();

    // ---- coalesced writeout (same pattern as R0 baseline) ----
    {
        const float4* src = (const float4*)sh2f;
        float4* dst = (float4*)(h2f_out + (size_t)blockIdx.x * F_SPB * H2D);
        #pragma unroll
        for (int i = t; i < (F_SPB * H2D) / 4; i += F_BLK) dst[i] = src[i];
        if (t < F_SPB)
            scl_out[blockIdx.x * F_SPB + t] = ((const float4*)ssc4)[t];
    }
}

// ---------------- K2: f32 backend GEMM + scale + store (R0-proven) ----------
#define K2_BLK  256
#define K2_SPB  64
#define K2_NBLK (BATCH / K2_SPB)           // 2048

__global__ __launch_bounds__(K2_BLK) void backend_kernel(
    const float* __restrict__ h2f_in, const float4* __restrict__ scl_in,
    const float* __restrict__ W3, const float* __restrict__ b3,
    float* __restrict__ out)
{
    __shared__ __align__(16) float sh2[K2_SPB * H2D];   // 5 KB
    __shared__ float4 ssc[K2_SPB];                      // 1 KB

    const int t = threadIdx.x;

    float w3r[3][H2D];
    float b3r[3];
    #pragma unroll
    for (int c = 0; c < 3; ++c) {
        const int j = t + K2_BLK * c;
        if (j < OUTD) {
            b3r[c] = b3[j];
            #pragma unroll
            for (int k = 0; k < H2D; ++k) w3r[c][k] = W3[k * OUTD + j];
        } else {
            b3r[c] = 0.0f;
            #pragma unroll
            for (int k = 0; k < H2D; ++k) w3r[c][k] = 0.0f;
        }
    }

    int bkt[3];
    #pragma unroll
    for (int c = 0; c < 3; ++c) {
        const int j = t + K2_BLK * c;
        int b = 0;
        if      (j >= 50  && j < 150) b = 1;
        else if (j >= 150 && j < 200) b = 2;
        else if (j >= 200 && j < 250) b = 3;
        else if (j >= 250 && j < 300) b = 4;
        bkt[c] = b;
    }

    const float4* h2src = (const float4*)(h2f_in + (size_t)blockIdx.x * K2_SPB * H2D);
    #pragma unroll
    for (int i = t; i < (K2_SPB * H2D) / 4; i += K2_BLK)
        ((float4*)sh2)[i] = h2src[i];
    if (t < K2_SPB) ssc[t] = scl_in[blockIdx.x * K2_SPB + t];
    __syncthreads();

    const size_t rowbase = (size_t)blockIdx.x * K2_SPB * OUTD;

    #pragma unroll 2
    for (int s = 0; s < K2_SPB; ++s) {
        float h[H2D];
        #pragma unroll
        for (int q5 = 0; q5 < 5; ++q5) {
            const float4 hv = *reinterpret_cast<const float4*>(&sh2[s * H2D + 4 * q5]);
            h[4 * q5 + 0] = hv.x; h[4 * q5 + 1] = hv.y;
            h[4 * q5 + 2] = hv.z; h[4 * q5 + 3] = hv.w;
        }
        const float4 sv = ssc[s];
        const size_t row = rowbase + (size_t)s * OUTD;
        #pragma unroll
        for (int c = 0; c < 3; ++c) {
            const int j = t + K2_BLK * c;
            if (j < OUTD) {
                float acc = b3r[c];
                #pragma unroll
                for (int k = 0; k < H2D; ++k) acc = fmaf(h[k], w3r[c][k], acc);
                float sc = 1.0f;
                if      (bkt[c] == 1) sc = sv.x;
                else if (bkt[c] == 2) sc = sv.y;
                else if (bkt[c] == 3) sc = sv.z;
                else if (bkt[c] == 4) sc = sv.w;
                out[row + j] = acc * sc;
            }
        }
    }
}

// ================= fallback: R2 fused kernel (proven, no workspace) ==========
#define BLK     256
#define SPB     64
#define NBLK    (BATCH / SPB)

__global__ __launch_bounds__(BLK) void fused_kernel(
    const float* __restrict__ x,
    const float* __restrict__ W1, const float* __restrict__ b1,
    const float* __restrict__ W2, const float* __restrict__ b2,
    const float* __restrict__ W3, const float* __restrict__ b3,
    float* __restrict__ out)
{
    __shared__ double w1d[2 * H1D];
    __shared__ double b1d[H1D];
    __shared__ double w2d[H1D * H2D];
    __shared__ double b2d[H2D];
    __shared__ float  xgs[50];
    __shared__ double cwd[50];
    __shared__ double cgd[4][H2D];
    __shared__ double cbd[4];
    __shared__ double sh1d[SPB * S1PAD];
    __shared__ double sh2d[SPB * S2PAD];
    __shared__ __align__(16) float sh2f[SPB * H2D];
    __shared__ __align__(16) float ssc4[SPB * 4];

    const int t  = threadIdx.x;
    const int ls = t & 63;
    const int lq = t >> 6;

    if (t < 2 * H1D) w1d[t] = (double)W1[t];
    if (t < H1D)     b1d[t] = (double)b1[t];
    for (int i = t; i < H1D * H2D; i += BLK) w2d[i] = (double)W2[i];
    if (t < H2D)     b2d[t] = (double)b2[t];
    if (t < 50) {
        volatile double m = (double)t * (7.0 / 49.0);
        double e = m + (-7.0);
        xgs[t] = (t == 49) ? 1.0f : (float)pow(10.0, e);
    }
    __syncthreads();

    if (t < 50) {
        float xp = (t < 49) ? xgs[t + 1] : xgs[t];
        float xm = (t > 0)  ? xgs[t - 1] : xgs[t];
        cwd[t] = 0.5 * ((double)xp - (double)xm);
    }
    __syncthreads();

    if (t < 4 * H2D) {
        const int q = t / H2D, k = t % H2D;
        const float* col = W3 + k * OUTD;
        double acc = 0.0;
        if (q == 0) {
            for (int i = 0; i < 50; ++i)
                acc = fma(cwd[i], (double)col[50 + i] + (double)col[100 + i], acc);
        } else {
            const int off = 100 + 50 * q;
            for (int i = 0; i < 50; ++i)
                acc = fma(cwd[i], (double)col[off + i], acc);
        }
        cgd[q][k] = acc;
    }
    if (t < 4) {
        const int q = t;
        double acc = 0.0;
        if (q == 0) {
            for (int i = 0; i < 50; ++i)
                acc = fma(cwd[i], (double)b3[50 + i] + (double)b3[100 + i], acc);
        } else {
            const int off = 100 + 50 * q;
            for (int i = 0; i < 50; ++i)
                acc = fma(cwd[i], (double)b3[off + i], acc);
        }
        cbd[q] = acc;
    }
    __syncthreads();

    {
        const int sid = blockIdx.x * SPB + ls;
        const double x0 = (double)x[sid * 2 + 0];
        const double x1 = (double)x[sid * 2 + 1];
        for (int k = lq; k < H1D; k += 4)
            sh1d[ls * S1PAD + k] =
                tanh(fma(x0, w1d[k], fma(x1, w1d[H1D + k], b1d[k])));
    }
    __syncthreads();

    {
        double acc2[5];
        #pragma unroll
        for (int i = 0; i < 5; ++i) acc2[i] = b2d[4 * i + lq];
        for (int k = 0; k < H1D; ++k) {
            const double hk = sh1d[ls * S1PAD + k];
            #pragma unroll
            for (int i = 0; i < 5; ++i)
                acc2[i] = fma(hk, w2d[k * H2D + 4 * i + lq], acc2[i]);
        }
        #pragma unroll
        for (int i = 0; i < 5; ++i) {
            const double h2v = tanh(acc2[i]);
            sh2d[ls * S2PAD + 4 * i + lq] = h2v;
            sh2f[ls * H2D  + 4 * i + lq] = (float)h2v;
        }
    }
    __syncthreads();

    {
        double acc = cbd[lq];
        #pragma unroll
        for (int k = 0; k < H2D; ++k)
            acc = fma(sh2d[ls * S2PAD + k], cgd[lq][k], acc);
        const double num = (lq & 1) ? 3.0 : 1.0;
        ssc4[ls * 4 + lq] = (float)(num / acc);
    }
    __syncthreads();

    float w3r[3][H2D];
    float b3r[3];
    #pragma unroll
    for (int c = 0; c < 3; ++c) {
        const int j = t + BLK * c;
        if (j < OUTD) {
            b3r[c] = b3[j];
            #pragma unroll
            for (int k = 0; k < H2D; ++k) w3r[c][k] = W3[k * OUTD + j];
        } else {
            b3r[c] = 0.0f;
            #pragma unroll
            for (int k = 0; k < H2D; ++k) w3r[c][k] = 0.0f;
        }
    }

    int bkt[3];
    #pragma unroll
    for (int c = 0; c < 3; ++c) {
        const int j = t + BLK * c;
        int b = 0;
        if      (j >= 50  && j < 150) b = 1;
        else if (j >= 150 && j < 200) b = 2;
        else if (j >= 200 && j < 250) b = 3;
        else if (j >= 250 && j < 300) b = 4;
        bkt[c] = b;
    }

    const size_t rowbase = (size_t)blockIdx.x * SPB * OUTD;

    for (int s = 0; s < SPB; ++s) {
        float h[H2D];
        #pragma unroll
        for (int q5 = 0; q5 < 5; ++q5) {
            const float4 hv = *reinterpret_cast<const float4*>(&sh2f[s * H2D + 4 * q5]);
            h[4 * q5 + 0] = hv.x; h[4 * q5 + 1] = hv.y;
            h[4 * q5 + 2] = hv.z; h[4 * q5 + 3] = hv.w;
        }
        const float4 sv = *reinterpret_cast<const float4*>(&ssc4[s * 4]);
        const size_t row = rowbase + (size_t)s * OUTD;
        #pragma unroll
        for (int c = 0; c < 3; ++c) {
            const int j = t + BLK * c;
            if (j < OUTD) {
                float acc = b3r[c];
                #pragma unroll
                for (int k = 0; k < H2D; ++k) acc = fmaf(h[k], w3r[c][k], acc);
                float sc = 1.0f;
                if      (bkt[c] == 1) sc = sv.x;
                else if (bkt[c] == 2) sc = sv.y;
                else if (bkt[c] == 3) sc = sv.z;
                else if (bkt[c] == 4) sc = sv.w;
                out[row + j] = acc * sc;
            }
        }
    }
}

extern "C" void kernel_launch(void* const* d_in, const int* in_sizes, int n_in,
                              void* d_out, int out_size, void* d_ws, size_t ws_size,
                              hipStream_t stream) {
    const float* x  = (const float*)d_in[0];
    const float* W1 = (const float*)d_in[1];
    const float* b1 = (const float*)d_in[2];
    const float* W2 = (const float*)d_in[3];
    const float* b2 = (const float*)d_in[4];
    const float* W3 = (const float*)d_in[5];
    const float* b3 = (const float*)d_in[6];
    float* out = (float*)d_out;

    if (ws_size >= WS_NEED && d_ws != nullptr) {
        float*  h2f = (float*) ((char*)d_ws + WS_H2F_OFF);
        float4* scl = (float4*)((char*)d_ws + WS_SCL_OFF);

        hipLaunchKernelGGL(frontend_split_kernel, dim3(F_NBLK), dim3(F_BLK), 0, stream,
                           x, W1, b1, W2, b2, W3, b3, h2f, scl);
        hipLaunchKernelGGL(backend_kernel, dim3(K2_NBLK), dim3(K2_BLK), 0, stream,
                           h2f, scl, W3, b3, out);
    } else {
        hipLaunchKernelGGL(fused_kernel, dim3(NBLK), dim3(BLK), 0, stream,
                           x, W1, b1, W2, b2, W3, b3, out);
    }
}